// Round 7
// baseline (187.987 us; speedup 1.0000x reference)
//
#include <hip/hip_runtime.h>
#include <math.h>

// ---------------------------------------------------------------------------
// Attention_2010044694851: x[4,2048,1024] fp32, w_qkv[1536,1024], w_out[1024,512],
// b_out[1024] -> out[4,2048,1024] fp32.
// cvt(weights) -> qkv_gemm (fp32 A reg-staged + bf16 B, V^T epilogue) ->
// causal sim GEMM -> softmax -> PV GEMM (reverse-bm) -> proj GEMM.
// GEMM core: 3-buffer depth-2 counted-vmcnt pipeline, swizzled conflict-free
// LDS (rule-21 both-sides), setprio MFMA, no scheduler pins on the read path.
// ---------------------------------------------------------------------------

typedef __attribute__((ext_vector_type(8))) short bf16x8_t;
typedef __attribute__((ext_vector_type(4))) float f32x4_t;

__device__ __forceinline__ unsigned short f2bf(float f) {
  unsigned int u = __float_as_uint(f);
  u = (u + 0x7FFFu + ((u >> 16) & 1u)) >> 16;
  return (unsigned short)u;
}
__device__ __forceinline__ float bf2f(unsigned short h) {
  return __uint_as_float(((unsigned int)h) << 16);
}

template <int N>
__device__ __forceinline__ void wait_vmcnt() {
  if constexpr (N == 0) asm volatile("s_waitcnt vmcnt(0)" ::: "memory");
  else if constexpr (N == 4) asm volatile("s_waitcnt vmcnt(4)" ::: "memory");
  else if constexpr (N == 6) asm volatile("s_waitcnt vmcnt(6)" ::: "memory");
}

// ---------------------------------------------------------------------------
// fp32 -> bf16 conversion for the two weight matrices (one launch)
// ---------------------------------------------------------------------------
__global__ __launch_bounds__(256) void cvt_w(
    const float* __restrict__ w1, unsigned short* __restrict__ w1b, int n1,
    const float* __restrict__ w2, unsigned short* __restrict__ w2b, int n2) {
  const int stride = gridDim.x * blockDim.x * 4;
  const int t0 = (blockIdx.x * blockDim.x + threadIdx.x) * 4;
  for (int i = t0; i < n1; i += stride) {
    float4 f = *(const float4*)(w1 + i);
    ushort4 u;
    u.x = f2bf(f.x); u.y = f2bf(f.y); u.z = f2bf(f.z); u.w = f2bf(f.w);
    *(ushort4*)(w1b + i) = u;
  }
  for (int i = t0; i < n2; i += stride) {
    float4 f = *(const float4*)(w2 + i);
    ushort4 u;
    u.x = f2bf(f.x); u.y = f2bf(f.y); u.z = f2bf(f.z); u.w = f2bf(f.w);
    *(ushort4*)(w2b + i) = u;
  }
}

// ---------------------------------------------------------------------------
// Causal row softmax in-place on sim [4][2048][2048] bf16. One wave per row;
// zero-fills to the 128-tile bound so PV can run full tiles with a K limit.
// ---------------------------------------------------------------------------
__global__ __launch_bounds__(256) void softmax_causal(unsigned short* __restrict__ sim) {
  const int lane = threadIdx.x & 63;
  const int rowg = blockIdx.x * 4 + (threadIdx.x >> 6);
  const int i = rowg & 2047;
  unsigned short* row = sim + (size_t)rowg * 2048;
  const int nv = i + 1;
  const int tb = ((i >> 7) + 1) << 7;
  const int nc = (nv + 255) >> 8;
  const int ns = (tb + 255) >> 8;

  float v[32];
  float m = -1e30f;
#pragma unroll
  for (int c = 0; c < 8; ++c) {
    if (c < nc) {
      const int j0 = c * 256 + lane * 4;
      ushort4 u = *(const ushort4*)(row + j0);
      float f0 = bf2f(u.x), f1 = bf2f(u.y), f2 = bf2f(u.z), f3 = bf2f(u.w);
      v[c * 4 + 0] = (j0 + 0 < nv) ? f0 : -1e30f;
      v[c * 4 + 1] = (j0 + 1 < nv) ? f1 : -1e30f;
      v[c * 4 + 2] = (j0 + 2 < nv) ? f2 : -1e30f;
      v[c * 4 + 3] = (j0 + 3 < nv) ? f3 : -1e30f;
      m = fmaxf(m, fmaxf(fmaxf(v[c * 4], v[c * 4 + 1]), fmaxf(v[c * 4 + 2], v[c * 4 + 3])));
    }
  }
#pragma unroll
  for (int s = 32; s >= 1; s >>= 1) m = fmaxf(m, __shfl_xor(m, s));
  float sum = 0.f;
#pragma unroll
  for (int c = 0; c < 8; ++c) {
    if (c < nc) {
#pragma unroll
      for (int e = 0; e < 4; ++e) {
        float p = __expf(v[c * 4 + e] - m);
        v[c * 4 + e] = p;
        sum += p;
      }
    }
  }
#pragma unroll
  for (int s = 32; s >= 1; s >>= 1) sum += __shfl_xor(sum, s);
  const float inv = 1.0f / sum;
#pragma unroll
  for (int c = 0; c < 8; ++c) {
    if (c < ns) {
      const int j0 = c * 256 + lane * 4;
      ushort4 u;
      if (c < nc) {
        u.x = f2bf(v[c * 4 + 0] * inv);
        u.y = f2bf(v[c * 4 + 1] * inv);
        u.z = f2bf(v[c * 4 + 2] * inv);
        u.w = f2bf(v[c * 4 + 3] * inv);
      } else {
        u.x = u.y = u.z = u.w = 0;
      }
      *(ushort4*)(row + j0) = u;
    }
  }
}

// ---------------------------------------------------------------------------
// QKV GEMM with fp32 A read directly (reg-staged + in-register f2bf), bf16 B
// via global_load_lds. C[8192,1536] = x[8192,1024] * wqkv[1536,1024]^T.
// Tile 128x128, BK=32, 4 waves. 3 LDS buffers, 2 tiles in flight,
// vmcnt(6) = (A:4 dwordx4 + B:2 gload_lds) per tile. A ds_writes drained by
// lgkmcnt(0) BEFORE the barrier (write-side pin only; read path unpinned).
// Epilogue scatters q*scale | k | V transposed.
// ---------------------------------------------------------------------------
__global__ __launch_bounds__(256) void qkv_gemm(
    const float* __restrict__ X, const unsigned short* __restrict__ B,
    unsigned short* __restrict__ Q, unsigned short* __restrict__ Kc,
    unsigned short* __restrict__ VT, float qscale) {
  constexpr int BM = 128, BN = 128, K = 1024;
  constexpr int FM = 4, FN = 4;
  constexpr int nkt = K / 32;  // 32
  const int bm = blockIdx.x, bn = blockIdx.y;
  const int tid = threadIdx.x, lane = tid & 63, wave = tid >> 6;
  const int wr = wave >> 1, wc = wave & 1;

  __shared__ alignas(16) unsigned short As[3][BM * 32];
  __shared__ alignas(16) unsigned short Bs[3][BN * 32];

  const float* Xb = X + (size_t)bm * BM * K;
  const unsigned short* Bb = B + (size_t)bn * BN * K;

  // A staging geometry: thread t -> row ar=t>>1, k-half ah=t&1 (16 elems)
  const int ar = tid >> 1, ah = tid & 1;
  const float* asrc = Xb + (size_t)ar * K + ah * 16;
  const int asw = (ar >> 1) & 3;                    // row swizzle
  char* arow = (char*)nullptr;                      // set per-buffer below

  float4 arA[4], arB[4];

  auto aloadA = [&](int kt) {
#pragma unroll
    for (int j = 0; j < 4; ++j) arA[j] = *(const float4*)(asrc + kt * 32 + j * 4);
  };
  auto aloadB = [&](int kt) {
#pragma unroll
    for (int j = 0; j < 4; ++j) arB[j] = *(const float4*)(asrc + kt * 32 + j * 4);
  };
  auto awrite = [&](int buf, const float4* a) {
    bf16x8_t lo, hi;
#pragma unroll
    for (int j = 0; j < 2; ++j) {
      lo[j * 4 + 0] = (short)f2bf(a[j].x);
      lo[j * 4 + 1] = (short)f2bf(a[j].y);
      lo[j * 4 + 2] = (short)f2bf(a[j].z);
      lo[j * 4 + 3] = (short)f2bf(a[j].w);
      hi[j * 4 + 0] = (short)f2bf(a[j + 2].x);
      hi[j * 4 + 1] = (short)f2bf(a[j + 2].y);
      hi[j * 4 + 2] = (short)f2bf(a[j + 2].z);
      hi[j * 4 + 3] = (short)f2bf(a[j + 2].w);
    }
    char* base = (char*)As[buf] + ar * 64;
    *(bf16x8_t*)(base + ((2 * ah + 0) ^ asw) * 16) = lo;
    *(bf16x8_t*)(base + ((2 * ah + 1) ^ asw) * 16) = hi;
  };
  auto bstage = [&](int buf, int kt) {
    const int loff = tid * 16;
#pragma unroll
    for (int i = 0; i < 2; ++i) {
      const int o = i * 4096 + loff;
      const int r = o >> 6;
      const int sl = ((o >> 4) & 3) ^ ((r >> 1) & 3);
      __builtin_amdgcn_global_load_lds(
          (const __attribute__((address_space(1))) void*)(
              (const char*)(Bb + (size_t)r * K) + (size_t)kt * 64 + sl * 16),
          (__attribute__((address_space(3))) void*)((char*)Bs[buf] + o), 16, 0, 0);
    }
  };

  f32x4_t acc[FM][FN] = {};

  aloadA(0); bstage(0, 0);
  aloadB(1); bstage(1, 1);
  int cur = 0;
  for (int kt = 0; kt < nkt; ++kt) {
    if (kt + 1 < nkt) wait_vmcnt<6>();  // tile kt landed; kt+1 in flight
    else wait_vmcnt<0>();
    if ((kt & 1) == 0) awrite(cur, arA); else awrite(cur, arB);
    asm volatile("s_waitcnt lgkmcnt(0)" ::: "memory");  // ds_writes visible
    __builtin_amdgcn_s_barrier();
    if (kt + 2 < nkt) {
      if ((kt & 1) == 0) aloadA(kt + 2); else aloadB(kt + 2);
      int nb = cur + 2;
      if (nb >= 3) nb -= 3;
      bstage(nb, kt + 2);
    }
    bf16x8_t av[FM], bv[FN];
#pragma unroll
    for (int f = 0; f < FM; ++f) {
      const int row = wr * 64 + f * 16 + (lane & 15);
      const int sp = (lane >> 4) ^ ((row >> 1) & 3);
      av[f] = *(const bf16x8_t*)((const char*)As[cur] + row * 64 + sp * 16);
    }
#pragma unroll
    for (int f = 0; f < FN; ++f) {
      const int row = wc * 64 + f * 16 + (lane & 15);
      const int sp = (lane >> 4) ^ ((row >> 1) & 3);
      bv[f] = *(const bf16x8_t*)((const char*)Bs[cur] + row * 64 + sp * 16);
    }
    __builtin_amdgcn_s_setprio(1);
#pragma unroll
    for (int fi = 0; fi < FM; ++fi)
#pragma unroll
      for (int fj = 0; fj < FN; ++fj)
        acc[fi][fj] = __builtin_amdgcn_mfma_f32_16x16x32_bf16(av[fi], bv[fj], acc[fi][fj], 0, 0, 0);
    __builtin_amdgcn_s_setprio(0);
    cur = (cur + 1 == 3) ? 0 : cur + 1;
  }

#pragma unroll
  for (int fi = 0; fi < FM; ++fi) {
    const int row_l = wr * 64 + fi * 16 + ((lane >> 4) << 2);
#pragma unroll
    for (int fj = 0; fj < FN; ++fj) {
      const int col = bn * BN + wc * 64 + fj * 16 + (lane & 15);
      const int row0 = bm * BM + row_l;
      if (col < 512) {
#pragma unroll
        for (int r = 0; r < 4; ++r)
          Q[(size_t)(row0 + r) * 512 + col] = f2bf(acc[fi][fj][r] * qscale);
      } else if (col < 1024) {
#pragma unroll
        for (int r = 0; r < 4; ++r)
          Kc[(size_t)(row0 + r) * 512 + (col - 512)] = f2bf(acc[fi][fj][r]);
      } else {
        const int e = col - 1024;
        const int b = row0 >> 11, n0 = row0 & 2047;
        ushort4 u;
        u.x = f2bf(acc[fi][fj][0]);
        u.y = f2bf(acc[fi][fj][1]);
        u.z = f2bf(acc[fi][fj][2]);
        u.w = f2bf(acc[fi][fj][3]);
        *(ushort4*)(VT + ((size_t)b * 512 + e) * 2048 + n0) = u;
      }
    }
  }
}

// ---------------------------------------------------------------------------
// bf16 B^T GEMM (unchanged R6 core): C[M,N] = A[M,K] * B[N,K]^T.
// EPI: 1 sim bf16  2 attn-out bf16  3 fp32+bias.  REV reverses bm so PV's
// longest-K tiles dispatch first (tail packing).
// ---------------------------------------------------------------------------
template <int EPI, int BM, int BN, int REV>
__global__ __launch_bounds__(256) void gemm_bt(
    const unsigned short* __restrict__ A, const unsigned short* __restrict__ B,
    int M, int N, int K, long strideA, long strideB, int klim, int causal,
    void* __restrict__ O0, const float* __restrict__ bias) {
  const int bm = REV ? (gridDim.x - 1 - blockIdx.x) : blockIdx.x;
  const int bn = blockIdx.y, bz = blockIdx.z;
  if (causal && bn > bm) return;
  const int tid = threadIdx.x, lane = tid & 63, wave = tid >> 6;
  const int wr = wave >> 1, wc = wave & 1;
  constexpr int FM = BM / 32, FN = BN / 32;
  constexpr int AR = BM / 64, BR = BN / 64;
  constexpr int L = AR + BR;

  __shared__ alignas(16) unsigned short As[3][BM * 32];
  __shared__ alignas(16) unsigned short Bs[3][BN * 32];

  const unsigned short* Ab = A + (size_t)bz * strideA + (size_t)bm * BM * K;
  const unsigned short* Bb = B + (size_t)bz * strideB + (size_t)bn * BN * K;

  const int kmax = klim ? min(K, (bm + 1) * BM) : K;
  const int nkt = kmax >> 5;

  auto stage = [&](int buf, int kt) {
    const int loff = tid * 16;
#pragma unroll
    for (int i = 0; i < AR; ++i) {
      const int o = i * 4096 + loff;
      const int r = o >> 6;
      const int sl = ((o >> 4) & 3) ^ ((r >> 1) & 3);
      __builtin_amdgcn_global_load_lds(
          (const __attribute__((address_space(1))) void*)(
              (const char*)(Ab + (size_t)r * K) + (size_t)kt * 64 + sl * 16),
          (__attribute__((address_space(3))) void*)((char*)As[buf] + o), 16, 0, 0);
    }
#pragma unroll
    for (int i = 0; i < BR; ++i) {
      const int o = i * 4096 + loff;
      const int r = o >> 6;
      const int sl = ((o >> 4) & 3) ^ ((r >> 1) & 3);
      __builtin_amdgcn_global_load_lds(
          (const __attribute__((address_space(1))) void*)(
              (const char*)(Bb + (size_t)r * K) + (size_t)kt * 64 + sl * 16),
          (__attribute__((address_space(3))) void*)((char*)Bs[buf] + o), 16, 0, 0);
    }
  };

  f32x4_t acc[FM][FN] = {};

  stage(0, 0);
  if (nkt > 1) stage(1, 1);
  int cur = 0;
  for (int kt = 0; kt < nkt; ++kt) {
    if (kt + 1 < nkt) wait_vmcnt<L>();
    else wait_vmcnt<0>();
    __builtin_amdgcn_s_barrier();

    bf16x8_t av[FM], bv[FN];
#pragma unroll
    for (int f = 0; f < FM; ++f) {
      const int row = wr * (BM / 2) + f * 16 + (lane & 15);
      const int sp = (lane >> 4) ^ ((row >> 1) & 3);
      av[f] = *(const bf16x8_t*)((const char*)As[cur] + row * 64 + sp * 16);
    }
#pragma unroll
    for (int f = 0; f < FN; ++f) {
      const int row = wc * (BN / 2) + f * 16 + (lane & 15);
      const int sp = (lane >> 4) ^ ((row >> 1) & 3);
      bv[f] = *(const bf16x8_t*)((const char*)Bs[cur] + row * 64 + sp * 16);
    }
    if (kt + 2 < nkt) {
      int nb = cur + 2;
      if (nb >= 3) nb -= 3;
      stage(nb, kt + 2);
    }
    __builtin_amdgcn_s_setprio(1);
#pragma unroll
    for (int fi = 0; fi < FM; ++fi)
#pragma unroll
      for (int fj = 0; fj < FN; ++fj)
        acc[fi][fj] = __builtin_amdgcn_mfma_f32_16x16x32_bf16(av[fi], bv[fj], acc[fi][fj], 0, 0, 0);
    __builtin_amdgcn_s_setprio(0);
    cur = (cur + 1 == 3) ? 0 : cur + 1;
  }

#pragma unroll
  for (int fi = 0; fi < FM; ++fi) {
    const int row_l = wr * (BM / 2) + fi * 16 + ((lane >> 4) << 2);
#pragma unroll
    for (int fj = 0; fj < FN; ++fj) {
      const int col = bn * BN + wc * (BN / 2) + fj * 16 + (lane & 15);
#pragma unroll
      for (int r = 0; r < 4; ++r) {
        const int row = bm * BM + row_l + r;
        float v = acc[fi][fj][r];
        if constexpr (EPI == 1) {
          ((unsigned short*)O0)[(size_t)bz * 2048 * 2048 + (size_t)row * 2048 + col] = f2bf(v);
        } else if constexpr (EPI == 2) {
          ((unsigned short*)O0)[(size_t)bz * 2048 * 512 + (size_t)row * 512 + col] = f2bf(v);
        } else {
          ((float*)O0)[(size_t)row * 1024 + col] = v + bias[col];
        }
      }
    }
  }
}

// ---------------------------------------------------------------------------
extern "C" void kernel_launch(void* const* d_in, const int* in_sizes, int n_in,
                              void* d_out, int out_size, void* d_ws, size_t ws_size,
                              hipStream_t stream) {
  const float* x = (const float*)d_in[0];
  const float* w_qkv = (const float*)d_in[1];
  const float* w_out = (const float*)d_in[2];
  const float* b_out = (const float*)d_in[3];
  float* out = (float*)d_out;

  char* ws = (char*)d_ws;
  size_t off = 0;
  auto alloc = [&](size_t bytes) {
    size_t o = off;
    off += (bytes + 255) & ~(size_t)255;
    return o;
  };
  unsigned short* wqkvb = (unsigned short*)(ws + alloc((size_t)1536 * 1024 * 2));
  unsigned short* woutb = (unsigned short*)(ws + alloc((size_t)1024 * 512 * 2));
  unsigned short* qb = (unsigned short*)(ws + alloc((size_t)8192 * 512 * 2));
  unsigned short* kb = (unsigned short*)(ws + alloc((size_t)8192 * 512 * 2));
  unsigned short* vtb = (unsigned short*)(ws + alloc((size_t)8192 * 512 * 2));
  unsigned short* sim = (unsigned short*)(ws + alloc((size_t)4 * 2048 * 2048 * 2));
  unsigned short* ao = (unsigned short*)(ws + alloc((size_t)8192 * 512 * 2));

  const float scale = 1.0f / sqrtf(512.0f);

  // weights fp32 -> bf16 (x is consumed fp32 directly by qkv_gemm)
  cvt_w<<<512, 256, 0, stream>>>(w_qkv, wqkvb, 1536 * 1024, w_out, woutb, 1024 * 512);

  // QKV: [8192,1536] = x[8192,1024](fp32) * wqkvb^T; V written transposed.
  qkv_gemm<<<dim3(64, 12), 256, 0, stream>>>(x, wqkvb, qb, kb, vtb, scale);

  // sim = q*scale @ k^T, causal tile skip
  gemm_bt<1, 128, 128, 0><<<dim3(16, 16, 4), 256, 0, stream>>>(
      qb, kb, 2048, 2048, 512, (long)2048 * 512, (long)2048 * 512,
      0, 1, sim, nullptr);

  softmax_causal<<<2048, 256, 0, stream>>>(sim);

  // attn @ v : 128x64 tile, K causal-limited, longest-K blocks first
  gemm_bt<2, 128, 64, 1><<<dim3(16, 8, 4), 256, 0, stream>>>(
      sim, vtb, 2048, 512, 2048, (long)2048 * 2048, (long)512 * 2048,
      1, 0, ao, nullptr);

  // out = ao @ w_out^T + b
  gemm_bt<3, 128, 128, 0><<<dim3(64, 8, 1), 256, 0, stream>>>(
      ao, woutb, 8192, 1024, 512, 0, 0, 0, 0, out, b_out);
}

// Round 9
// 128.257 us; speedup vs baseline: 1.4657x; 1.4657x over previous
//
#include <hip/hip_runtime.h>
#include <math.h>

// ---------------------------------------------------------------------------
// Attention_2010044694851: x[4,2048,1024] fp32, w_qkv[1536,1024], w_out[1024,512],
// b_out[1024] -> out[4,2048,1024] fp32.
// cvt(all) -> QKV GEMM (V^T epilogue) -> causal sim GEMM (triangular grid) ->
// softmax -> PV GEMM (64x128, reverse-bm) -> proj GEMM.
// GEMM core (R6-proven, 134µs): 3-buffer depth-2 counted-vmcnt pipeline,
// swizzled conflict-free LDS (rule-21 both-sides), setprio MFMA, no pins.
// R7 lesson: fp32-A reg-staging = 3x regression (m151) — reverted.
// ---------------------------------------------------------------------------

typedef __attribute__((ext_vector_type(8))) short bf16x8_t;
typedef __attribute__((ext_vector_type(4))) float f32x4_t;

__device__ __forceinline__ unsigned short f2bf(float f) {
  unsigned int u = __float_as_uint(f);
  u = (u + 0x7FFFu + ((u >> 16) & 1u)) >> 16;
  return (unsigned short)u;
}
__device__ __forceinline__ float bf2f(unsigned short h) {
  return __uint_as_float(((unsigned int)h) << 16);
}

template <int N>
__device__ __forceinline__ void wait_vmcnt() {
  if constexpr (N == 0) asm volatile("s_waitcnt vmcnt(0)" ::: "memory");
  else if constexpr (N == 3) asm volatile("s_waitcnt vmcnt(3)" ::: "memory");
  else if constexpr (N == 4) asm volatile("s_waitcnt vmcnt(4)" ::: "memory");
  else if constexpr (N == 6) asm volatile("s_waitcnt vmcnt(6)" ::: "memory");
}

// ---------------------------------------------------------------------------
// fused fp32 -> bf16 conversion for all three inputs (one launch)
// ---------------------------------------------------------------------------
__global__ __launch_bounds__(256) void cvt_all(
    const float* __restrict__ x, unsigned short* __restrict__ xb, int nx,
    const float* __restrict__ w1, unsigned short* __restrict__ w1b, int n1,
    const float* __restrict__ w2, unsigned short* __restrict__ w2b, int n2) {
  const int stride = gridDim.x * blockDim.x * 4;
  const int t0 = (blockIdx.x * blockDim.x + threadIdx.x) * 4;
  for (int i = t0; i < nx; i += stride) {
    float4 f = *(const float4*)(x + i);
    ushort4 u;
    u.x = f2bf(f.x); u.y = f2bf(f.y); u.z = f2bf(f.z); u.w = f2bf(f.w);
    *(ushort4*)(xb + i) = u;
  }
  for (int i = t0; i < n1; i += stride) {
    float4 f = *(const float4*)(w1 + i);
    ushort4 u;
    u.x = f2bf(f.x); u.y = f2bf(f.y); u.z = f2bf(f.z); u.w = f2bf(f.w);
    *(ushort4*)(w1b + i) = u;
  }
  for (int i = t0; i < n2; i += stride) {
    float4 f = *(const float4*)(w2 + i);
    ushort4 u;
    u.x = f2bf(f.x); u.y = f2bf(f.y); u.z = f2bf(f.z); u.w = f2bf(f.w);
    *(ushort4*)(w2b + i) = u;
  }
}

// ---------------------------------------------------------------------------
// Causal row softmax in-place on sim [4][2048][2048] bf16. One wave per row;
// zero-fills to the 64-row-tile bound (PV tiles are 64 rows -> K limit 64-granular).
// ---------------------------------------------------------------------------
__global__ __launch_bounds__(256) void softmax_causal(unsigned short* __restrict__ sim) {
  const int lane = threadIdx.x & 63;
  const int rowg = blockIdx.x * 4 + (threadIdx.x >> 6);
  const int i = rowg & 2047;
  unsigned short* row = sim + (size_t)rowg * 2048;
  const int nv = i + 1;
  const int tb = ((i >> 6) + 1) << 6;   // 64-tile bound
  const int nc = (nv + 255) >> 8;
  const int ns = (tb + 255) >> 8;

  float v[32];
  float m = -1e30f;
#pragma unroll
  for (int c = 0; c < 8; ++c) {
    if (c < nc) {
      const int j0 = c * 256 + lane * 4;
      ushort4 u = *(const ushort4*)(row + j0);
      float f0 = bf2f(u.x), f1 = bf2f(u.y), f2 = bf2f(u.z), f3 = bf2f(u.w);
      v[c * 4 + 0] = (j0 + 0 < nv) ? f0 : -1e30f;
      v[c * 4 + 1] = (j0 + 1 < nv) ? f1 : -1e30f;
      v[c * 4 + 2] = (j0 + 2 < nv) ? f2 : -1e30f;
      v[c * 4 + 3] = (j0 + 3 < nv) ? f3 : -1e30f;
      m = fmaxf(m, fmaxf(fmaxf(v[c * 4], v[c * 4 + 1]), fmaxf(v[c * 4 + 2], v[c * 4 + 3])));
    }
  }
#pragma unroll
  for (int s = 32; s >= 1; s >>= 1) m = fmaxf(m, __shfl_xor(m, s));
  float sum = 0.f;
#pragma unroll
  for (int c = 0; c < 8; ++c) {
    if (c < nc) {
#pragma unroll
      for (int e = 0; e < 4; ++e) {
        float p = __expf(v[c * 4 + e] - m);
        v[c * 4 + e] = p;
        sum += p;
      }
    }
  }
#pragma unroll
  for (int s = 32; s >= 1; s >>= 1) sum += __shfl_xor(sum, s);
  const float inv = 1.0f / sum;
#pragma unroll
  for (int c = 0; c < 8; ++c) {
    if (c < ns) {
      const int j0 = c * 256 + lane * 4;
      ushort4 u;
      if (c < nc) {
        u.x = f2bf(v[c * 4 + 0] * inv);
        u.y = f2bf(v[c * 4 + 1] * inv);
        u.z = f2bf(v[c * 4 + 2] * inv);
        u.w = f2bf(v[c * 4 + 3] * inv);
      } else {
        u.x = u.y = u.z = u.w = 0;
      }
      *(ushort4*)(row + j0) = u;
    }
  }
}

// ---------------------------------------------------------------------------
// bf16 B^T GEMM: C[M,N] = A[M,K] * B[N,K]^T. Tile BMxBN (mult of 64), BK=32,
// 4 waves (2x2), per-wave (BM/2)x(BN/2). 3 LDS buffers, 2 tiles in flight,
// steady-state wait = vmcnt(loads/tile) — never 0 in the main loop.
// Race ledger: iter-kt barrier crossed only after each wave's iter-(kt-1)
// ds_reads completed (MFMA consumers precede it); stage(kt+2) overwrites tile
// (kt-1)'s buffer post-barrier -> safe. Swizzle phys16Bslot = slot^((row>>1)&3)
// on BOTH stage-src and ds_read (rule 21); measured 0 conflicts.
// EPI: 0 QKV scatter (q*scale | k | V^T)  1 sim  2 attn-out  3 fp32+bias
// TRI: decode (bm,bn) from blockIdx.x as packed lower triangle, bz=blockIdx.y.
// REV: reverse bm (longest-K first when klim).
// ---------------------------------------------------------------------------
template <int EPI, int BM, int BN, int REV, int TRI>
__global__ __launch_bounds__(256) void gemm_bt(
    const unsigned short* __restrict__ A, const unsigned short* __restrict__ B,
    int M, int N, int K, long strideA, long strideB, int klim,
    void* __restrict__ O0, void* __restrict__ O1, void* __restrict__ O2,
    const float* __restrict__ bias, float qscale) {
  int bm, bn, bz;
  if constexpr (TRI) {
    const int bid = blockIdx.x;
    bm = (int)((sqrtf(8.f * (float)bid + 1.f) - 1.f) * 0.5f);
    while ((bm + 1) * (bm + 2) / 2 <= bid) ++bm;
    while (bm * (bm + 1) / 2 > bid) --bm;
    bn = bid - bm * (bm + 1) / 2;
    bz = blockIdx.y;
  } else {
    bm = REV ? (gridDim.x - 1 - blockIdx.x) : blockIdx.x;
    bn = blockIdx.y;
    bz = blockIdx.z;
  }
  const int tid = threadIdx.x, lane = tid & 63, wave = tid >> 6;
  const int wr = wave >> 1, wc = wave & 1;
  constexpr int FM = BM / 32, FN = BN / 32;
  constexpr int AR = BM / 64, BR = BN / 64;
  constexpr int L = AR + BR;

  __shared__ alignas(16) unsigned short As[3][BM * 32];
  __shared__ alignas(16) unsigned short Bs[3][BN * 32];

  const unsigned short* Ab = A + (size_t)bz * strideA + (size_t)bm * BM * K;
  const unsigned short* Bb = B + (size_t)bz * strideB + (size_t)bn * BN * K;

  const int kmax = klim ? min(K, (bm + 1) * BM) : K;
  const int nkt = kmax >> 5;

  auto stage = [&](int buf, int kt) {
    const int loff = tid * 16;
#pragma unroll
    for (int i = 0; i < AR; ++i) {
      const int o = i * 4096 + loff;
      const int r = o >> 6;
      const int sl = ((o >> 4) & 3) ^ ((r >> 1) & 3);
      __builtin_amdgcn_global_load_lds(
          (const __attribute__((address_space(1))) void*)(
              (const char*)(Ab + (size_t)r * K) + (size_t)kt * 64 + sl * 16),
          (__attribute__((address_space(3))) void*)((char*)As[buf] + o), 16, 0, 0);
    }
#pragma unroll
    for (int i = 0; i < BR; ++i) {
      const int o = i * 4096 + loff;
      const int r = o >> 6;
      const int sl = ((o >> 4) & 3) ^ ((r >> 1) & 3);
      __builtin_amdgcn_global_load_lds(
          (const __attribute__((address_space(1))) void*)(
              (const char*)(Bb + (size_t)r * K) + (size_t)kt * 64 + sl * 16),
          (__attribute__((address_space(3))) void*)((char*)Bs[buf] + o), 16, 0, 0);
    }
  };

  f32x4_t acc[FM][FN] = {};

  stage(0, 0);
  if (nkt > 1) stage(1, 1);
  int cur = 0;
  for (int kt = 0; kt < nkt; ++kt) {
    if (kt + 1 < nkt) wait_vmcnt<L>();
    else wait_vmcnt<0>();
    __builtin_amdgcn_s_barrier();

    bf16x8_t av[FM], bv[FN];
#pragma unroll
    for (int f = 0; f < FM; ++f) {
      const int row = wr * (BM / 2) + f * 16 + (lane & 15);
      const int sp = (lane >> 4) ^ ((row >> 1) & 3);
      av[f] = *(const bf16x8_t*)((const char*)As[cur] + row * 64 + sp * 16);
    }
#pragma unroll
    for (int f = 0; f < FN; ++f) {
      const int row = wc * (BN / 2) + f * 16 + (lane & 15);
      const int sp = (lane >> 4) ^ ((row >> 1) & 3);
      bv[f] = *(const bf16x8_t*)((const char*)Bs[cur] + row * 64 + sp * 16);
    }
    if (kt + 2 < nkt) {
      int nb = cur + 2;
      if (nb >= 3) nb -= 3;
      stage(nb, kt + 2);
    }
    __builtin_amdgcn_s_setprio(1);
#pragma unroll
    for (int fi = 0; fi < FM; ++fi)
#pragma unroll
      for (int fj = 0; fj < FN; ++fj)
        acc[fi][fj] = __builtin_amdgcn_mfma_f32_16x16x32_bf16(av[fi], bv[fj], acc[fi][fj], 0, 0, 0);
    __builtin_amdgcn_s_setprio(0);
    cur = (cur + 1 == 3) ? 0 : cur + 1;
  }

#pragma unroll
  for (int fi = 0; fi < FM; ++fi) {
    const int row_l = wr * (BM / 2) + fi * 16 + ((lane >> 4) << 2);
#pragma unroll
    for (int fj = 0; fj < FN; ++fj) {
      const int col = bn * BN + wc * (BN / 2) + fj * 16 + (lane & 15);
      if constexpr (EPI == 0) {
        const int row0 = bm * BM + row_l;
        if (col < 512) {
#pragma unroll
          for (int r = 0; r < 4; ++r)
            ((unsigned short*)O0)[(size_t)(row0 + r) * 512 + col] =
                f2bf(acc[fi][fj][r] * qscale);
        } else if (col < 1024) {
#pragma unroll
          for (int r = 0; r < 4; ++r)
            ((unsigned short*)O1)[(size_t)(row0 + r) * 512 + (col - 512)] =
                f2bf(acc[fi][fj][r]);
        } else {
          // V transposed: vtb[b][e][n], e = col-1024, n = row within batch.
          const int e = col - 1024;
          const int b = row0 >> 11, n0 = row0 & 2047;
          ushort4 u;
          u.x = f2bf(acc[fi][fj][0]);
          u.y = f2bf(acc[fi][fj][1]);
          u.z = f2bf(acc[fi][fj][2]);
          u.w = f2bf(acc[fi][fj][3]);
          *(ushort4*)((unsigned short*)O2 + ((size_t)b * 512 + e) * 2048 + n0) = u;
        }
      } else {
#pragma unroll
        for (int r = 0; r < 4; ++r) {
          const int row = bm * BM + row_l + r;
          float v = acc[fi][fj][r];
          if constexpr (EPI == 1) {
            ((unsigned short*)O0)[(size_t)bz * 2048 * 2048 + (size_t)row * 2048 + col] = f2bf(v);
          } else if constexpr (EPI == 2) {
            ((unsigned short*)O0)[(size_t)bz * 2048 * 512 + (size_t)row * 512 + col] = f2bf(v);
          } else {
            ((float*)O0)[(size_t)row * 1024 + col] = v + bias[col];
          }
        }
      }
    }
  }
}

// ---------------------------------------------------------------------------
extern "C" void kernel_launch(void* const* d_in, const int* in_sizes, int n_in,
                              void* d_out, int out_size, void* d_ws, size_t ws_size,
                              hipStream_t stream) {
  const float* x = (const float*)d_in[0];
  const float* w_qkv = (const float*)d_in[1];
  const float* w_out = (const float*)d_in[2];
  const float* b_out = (const float*)d_in[3];
  float* out = (float*)d_out;

  char* ws = (char*)d_ws;
  size_t off = 0;
  auto alloc = [&](size_t bytes) {
    size_t o = off;
    off += (bytes + 255) & ~(size_t)255;
    return o;
  };
  unsigned short* xb = (unsigned short*)(ws + alloc((size_t)8192 * 1024 * 2));
  unsigned short* wqkvb = (unsigned short*)(ws + alloc((size_t)1536 * 1024 * 2));
  unsigned short* woutb = (unsigned short*)(ws + alloc((size_t)1024 * 512 * 2));
  unsigned short* qb = (unsigned short*)(ws + alloc((size_t)8192 * 512 * 2));
  unsigned short* kb = (unsigned short*)(ws + alloc((size_t)8192 * 512 * 2));
  unsigned short* vtb = (unsigned short*)(ws + alloc((size_t)8192 * 512 * 2));
  unsigned short* sim = (unsigned short*)(ws + alloc((size_t)4 * 2048 * 2048 * 2));
  unsigned short* ao = (unsigned short*)(ws + alloc((size_t)8192 * 512 * 2));

  const float scale = 1.0f / sqrtf(512.0f);

  cvt_all<<<2048, 256, 0, stream>>>(x, xb, 8192 * 1024, w_qkv, wqkvb, 1536 * 1024,
                                    w_out, woutb, 1024 * 512);

  // QKV: [8192,1536] = xb[8192,1024] * wqkvb^T; V written transposed.
  // 48KB LDS -> 3 blocks/CU.
  gemm_bt<0, 128, 128, 0, 0><<<dim3(64, 12, 1), 256, 0, stream>>>(
      xb, wqkvb, 8192, 1536, 1024, 0, 0, 0, qb, kb, vtb, nullptr, scale);

  // sim = q*scale @ k^T — packed lower-triangular grid (136 tiles x 4 batches)
  gemm_bt<1, 128, 128, 0, 1><<<dim3(136, 4, 1), 256, 0, stream>>>(
      qb, kb, 2048, 2048, 512, (long)2048 * 512, (long)2048 * 512,
      0, sim, nullptr, nullptr, nullptr, 0.f);

  softmax_causal<<<2048, 256, 0, stream>>>(sim);

  // attn @ v : 64x128 tile (36KB LDS -> 4 blocks/CU), 64-granular K limit,
  // longest-K blocks first
  gemm_bt<2, 64, 128, 1, 0><<<dim3(32, 4, 4), 256, 0, stream>>>(
      sim, vtb, 2048, 512, 2048, (long)2048 * 2048, (long)512 * 2048,
      1, ao, nullptr, nullptr, nullptr, 0.f);

  // out = ao @ w_out^T + b
  gemm_bt<3, 128, 128, 0, 0><<<dim3(64, 8, 1), 256, 0, stream>>>(
      ao, woutb, 8192, 1024, 512, 0, 0, 0, out, nullptr, nullptr, b_out, 0.f);
}